// Round 4
// baseline (436.676 us; speedup 1.0000x reference)
//
#include <hip/hip_runtime.h>
#include <hip/hip_bf16.h>

// ComplexAttention: B=2, L=2048, D=1024, H=16, HD=64, SCALE=0.125
// Pipeline: pack(x,w) -> bf16 GEMM (producer-consumer waves, QKV, Q pre-scaled, V transposed)
//           -> flash attn (paired q-tiles, fixed-max softmax, ones-row l, async staging)
//           -> bf16 GEMM (+bias, fp32 out)
// GEMM core: 320 threads. Waves 0-3 = consumers (ds_read+MFMA only -> no vmcnt drain at
// their barriers). Wave 4 = producer: triple-buffered BK=32 staging via global_load_lds,
// issuing tile t+2 after barrier t, so its forced vmcnt(0)-before-barrier waits on loads
// that already had a full compute phase in flight.

using f32x4  = __attribute__((ext_vector_type(4))) float;
using short8 = __attribute__((ext_vector_type(8))) short;   // 8 bf16 = 4 VGPRs (MFMA A/B frag)
using bf16_t = __hip_bfloat16;

#define AS1 __attribute__((address_space(1)))
#define AS3 __attribute__((address_space(3)))

__device__ __forceinline__ void gload_lds16(const bf16_t* g, bf16_t* l) {
  __builtin_amdgcn_global_load_lds((const AS1 unsigned int*)g, (AS3 unsigned int*)l, 16, 0, 0);
}

__device__ __forceinline__ unsigned short bfbits(float f) {
  union { bf16_t h; unsigned short u; } c; c.h = __float2bfloat16(f); return c.u;
}

// ---------------------------------------------------------------- pack kernels
__global__ void pack_x_k(const float* __restrict__ xr, const float* __restrict__ xi,
                         bf16_t* __restrict__ out) {
  const int total4 = 4096 * 2048 / 4;
  for (int idx = blockIdx.x * blockDim.x + threadIdx.x; idx < total4;
       idx += gridDim.x * blockDim.x) {
    int m = idx >> 9, k = (idx & 511) * 4;
    const float* src = (k < 1024) ? (xr + (size_t)m * 1024 + k)
                                  : (xi + (size_t)m * 1024 + (k - 1024));
    float4 v = *(const float4*)src;
    unsigned int lo = (unsigned)bfbits(v.x) | ((unsigned)bfbits(v.y) << 16);
    unsigned int hi = (unsigned)bfbits(v.z) | ((unsigned)bfbits(v.w) << 16);
    *(uint2*)(out + (size_t)idx * 4) = make_uint2(lo, hi);
  }
}

__global__ void pack_wqkv_k(const float* __restrict__ wqr, const float* __restrict__ wqi,
                            const float* __restrict__ wkr, const float* __restrict__ wki,
                            const float* __restrict__ wvr, const float* __restrict__ wvi,
                            bf16_t* __restrict__ out) {
  const int total4 = 6144 * 2048 / 4;
  for (int idx = blockIdx.x * blockDim.x + threadIdx.x; idx < total4;
       idx += gridDim.x * blockDim.x) {
    int row = idx >> 9, k = (idx & 511) * 4;
    int sec = row >> 10, r1 = row & 1023;
    bool lowk = (k < 1024);
    int kk = lowk ? k : (k - 1024);
    const float* base = wqr; float sg = 1.f;
    switch (sec) {
      case 0: base = lowk ? wqr : wqi; sg = lowk ? 1.f : -1.f; break;
      case 1: base = lowk ? wqi : wqr; break;
      case 2: base = lowk ? wkr : wki; sg = lowk ? 1.f : -1.f; break;
      case 3: base = lowk ? wki : wkr; break;
      case 4: base = lowk ? wvr : wvi; sg = lowk ? 1.f : -1.f; break;
      case 5: base = lowk ? wvi : wvr; break;
    }
    float4 v = *(const float4*)(base + (size_t)r1 * 1024 + kk);
    unsigned int lo = (unsigned)bfbits(v.x * sg) | ((unsigned)bfbits(v.y * sg) << 16);
    unsigned int hi = (unsigned)bfbits(v.z * sg) | ((unsigned)bfbits(v.w * sg) << 16);
    *(uint2*)(out + (size_t)idx * 4) = make_uint2(lo, hi);
  }
}

__global__ void pack_wo_k(const float* __restrict__ wor, const float* __restrict__ woi,
                          bf16_t* __restrict__ out) {
  const int total4 = 2048 * 2048 / 4;
  for (int idx = blockIdx.x * blockDim.x + threadIdx.x; idx < total4;
       idx += gridDim.x * blockDim.x) {
    int row = idx >> 9, k = (idx & 511) * 4;
    int sec = row >> 10, r1 = row & 1023;
    bool lowk = (k < 1024);
    int kk = lowk ? k : (k - 1024);
    const float* base; float sg = 1.f;
    if (sec == 0) { base = lowk ? wor : woi; sg = lowk ? 1.f : -1.f; }
    else          { base = lowk ? woi : wor; }
    float4 v = *(const float4*)(base + (size_t)r1 * 1024 + kk);
    unsigned int lo = (unsigned)bfbits(v.x * sg) | ((unsigned)bfbits(v.y * sg) << 16);
    unsigned int hi = (unsigned)bfbits(v.z * sg) | ((unsigned)bfbits(v.w * sg) << 16);
    *(uint2*)(out + (size_t)idx * 4) = make_uint2(lo, hi);
  }
}

// ------------------------------------------------------- GEMM core, producer-consumer
// C[m,n] = sum_k A[m,k]*W[n,k]; A: Mx2048, W: Nx2048 bf16 row-major. 128x128 tile, BK=32,
// triple-buffered. LDS row = 32 elem = 4 chunks of 16 B; chunk' holds global chunk
// chunk'^(row&3). 320 threads: waves 0-3 consume, wave 4 produces.
__device__ __forceinline__ void gemm_core_pc(const bf16_t* __restrict__ A,
                                             const bf16_t* __restrict__ W,
                                             int m0, int n0, f32x4 (&acc)[4][4]) {
  __shared__ __align__(16) bf16_t sA[3][128 * 32];
  __shared__ __align__(16) bf16_t sB[3][128 * 32];
  const int tid = threadIdx.x, lane = tid & 63, w = tid >> 6;
  constexpr int T = 2048 / 32;  // 64 k-iterations

  if (w == 4) {
    // ---- producer wave: 16 gload_lds16 per tile (A 8 + B 8), 2-ahead issue
    const int r16 = lane >> 2;                 // row within 16-row group
    const int g8  = ((lane & 3) ^ (r16 & 3)) * 8;  // swizzled global chunk offset (elems)
    const bf16_t* Ab = A + (size_t)(m0 + r16) * 2048 + g8;
    const bf16_t* Wb = W + (size_t)(n0 + r16) * 2048 + g8;
#define ISSUE(t, s)                                                              \
    {                                                                            \
      const int k0_ = (t) * 32;                                                  \
      _Pragma("unroll")                                                          \
      for (int i = 0; i < 8; ++i) {                                              \
        gload_lds16(Ab + (size_t)(i * 16) * 2048 + k0_, sA[s] + i * 512 + lane * 8); \
        gload_lds16(Wb + (size_t)(i * 16) * 2048 + k0_, sB[s] + i * 512 + lane * 8); \
      }                                                                          \
    }
    ISSUE(0, 0);
    ISSUE(1, 1);
    for (int t = 0; t < T; ++t) {
      __syncthreads();   // compiler emits vmcnt(0) here: waits loads issued LAST iter
      if (t + 2 < T) ISSUE(t + 2, (t + 2) % 3);
    }
#undef ISSUE
  } else {
    // ---- consumer waves: no vmem ops in loop -> barriers cost only lgkmcnt
    const int wr = w >> 1, wc = w & 1;
    const int quad = lane >> 4, m16 = lane & 15;
    const int csw = (quad ^ (m16 & 3)) * 8;    // swizzled chunk for frag reads
    for (int t = 0; t < T; ++t) {
      __syncthreads();
      const bf16_t* bA = sA[t % 3];
      const bf16_t* bB = sB[t % 3];
      short8 af[4], bf[4];
#pragma unroll
      for (int i = 0; i < 4; ++i)
        af[i] = *(const short8*)(bA + (wr * 64 + i * 16 + m16) * 32 + csw);
#pragma unroll
      for (int j = 0; j < 4; ++j)
        bf[j] = *(const short8*)(bB + (wc * 64 + j * 16 + m16) * 32 + csw);
#pragma unroll
      for (int i = 0; i < 4; ++i)
#pragma unroll
        for (int j = 0; j < 4; ++j)
          acc[i][j] = __builtin_amdgcn_mfma_f32_16x16x32_bf16(af[i], bf[j], acc[i][j], 0, 0, 0);
    }
  }
}

// QKV GEMM: N=6144. cols 0..4095 -> qk buf [4096][4096] (Qr|Qi|Kr|Ki), Q pre-scaled by 0.125.
// cols 4096..6143 -> V transposed: vt[b*2048 + h*128 + ri*64 + d][seq]
__global__ __launch_bounds__(320) void gemm_qkv_k(const bf16_t* __restrict__ A,
                                                  const bf16_t* __restrict__ W,
                                                  bf16_t* __restrict__ qk,
                                                  bf16_t* __restrict__ vt) {
  f32x4 acc[4][4] = {};
  const int m0 = blockIdx.x * 128, n0 = blockIdx.y * 128;
  gemm_core_pc(A, W, m0, n0, acc);
  if (threadIdx.x >= 256) return;  // producer wave: no epilogue (no barriers below)
  const int lane = threadIdx.x & 63, w = threadIdx.x >> 6;
  const int wr = w >> 1, wc = w & 1, quad = lane >> 4, m16 = lane & 15;
#pragma unroll
  for (int i = 0; i < 4; ++i) {
    const int rowb = m0 + wr * 64 + i * 16 + quad * 4;  // C/D row = quad*4 + reg
#pragma unroll
    for (int j = 0; j < 4; ++j) {
      const int col = n0 + wc * 64 + j * 16 + m16;      // C/D col = lane&15
      if (col < 4096) {
        const float sc = (col < 2048) ? 0.125f : 1.f;   // pre-scale Q by SCALE
#pragma unroll
        for (int r = 0; r < 4; ++r)
          qk[(size_t)(rowb + r) * 4096 + col] = __float2bfloat16(acc[i][j][r] * sc);
      } else {
        const int vcol = col - 4096;
        const int ri = vcol >> 10, dfeat = vcol & 1023;
        const int b = rowb >> 11, seq = rowb & 2047;
        const size_t vrow = (size_t)(b * 2048 + (dfeat >> 6) * 128 + ri * 64 + (dfeat & 63));
        unsigned int lo = (unsigned)bfbits(acc[i][j][0]) | ((unsigned)bfbits(acc[i][j][1]) << 16);
        unsigned int hi = (unsigned)bfbits(acc[i][j][2]) | ((unsigned)bfbits(acc[i][j][3]) << 16);
        *(uint2*)(vt + vrow * 2048 + seq) = make_uint2(lo, hi);
      }
    }
  }
}

// Output GEMM: N=2048 ([yr|yi]), fp32 out + bias.
__global__ __launch_bounds__(320) void gemm_out_k(const bf16_t* __restrict__ A,
                                                  const bf16_t* __restrict__ W,
                                                  const float* __restrict__ bor,
                                                  const float* __restrict__ boi,
                                                  float* __restrict__ out) {
  f32x4 acc[4][4] = {};
  const int m0 = blockIdx.x * 128, n0 = blockIdx.y * 128;
  gemm_core_pc(A, W, m0, n0, acc);
  if (threadIdx.x >= 256) return;
  const int lane = threadIdx.x & 63, w = threadIdx.x >> 6;
  const int wr = w >> 1, wc = w & 1, quad = lane >> 4, m16 = lane & 15;
#pragma unroll
  for (int i = 0; i < 4; ++i) {
    const int rowb = m0 + wr * 64 + i * 16 + quad * 4;
#pragma unroll
    for (int j = 0; j < 4; ++j) {
      const int col = n0 + wc * 64 + j * 16 + m16;
      float bias; float* op;
      if (col < 1024) { bias = bor[col]; op = out + col; }
      else            { bias = boi[col - 1024]; op = out + 4194304 + (col - 1024); }
#pragma unroll
      for (int r = 0; r < 4; ++r)
        op[(size_t)(rowb + r) * 1024] = acc[i][j][r] + bias;
    }
  }
}

// ---------------------------------------------------------------- flash attention v3
// grid (16, B*H): block x handles q-subtiles A = x*64.. and B = (31-x)*64.. against a SHARED
// staged K/V tile (joint k-loop, BK=64). Fixed-max softmax, ones-row-MFMA row sums.
// K/V staged via global_load_lds + XOR chunk swizzle; sK stride 128, sV stride 64, sP 72.
__global__ __launch_bounds__(256, 2) void attn_k(const bf16_t* __restrict__ qk,
                                                 const bf16_t* __restrict__ vt,
                                                 bf16_t* __restrict__ acat) {
  __shared__ __align__(16) bf16_t sK[64 * 128];       // 16 KB
  __shared__ __align__(16) bf16_t sV[144 * 64];       // 18 KB (rows 128..143: ones/zeros)
  __shared__ __align__(16) bf16_t sP[4][2][16 * 72];  // 18 KB
  const int tid = threadIdx.x, lane = tid & 63, w = tid >> 6;
  const int quad = lane >> 4, m16 = lane & 15;
  const int x = blockIdx.x, bh = blockIdx.y, b = bh >> 4, h = bh & 15;
  const size_t qkrow0 = (size_t)b * 2048;
  const int qA = x * 64, qB = (31 - x) * 64;
  const int nT = 32 - x;
  const int swz7 = m16 & 7;

  // preset sV rows 128..143: row 128 = ones, rest zeros (constant rows: swizzle-invariant)
  {
    const int rr = tid >> 4, cb = (tid & 15) * 4;
    const bf16_t v = __float2bfloat16(rr == 0 ? 1.f : 0.f);
#pragma unroll
    for (int i = 0; i < 4; ++i) sV[(128 + rr) * 64 + cb + i] = v;
  }

  // Q fragments for both subtiles (A-operand: m=lane&15, k=quad*8+j), d-chunks of 32
  short8 qfA[4], qfB[4];
  {
    const bf16_t* qa = qk + (qkrow0 + qA + w * 16 + m16) * 4096;
    const bf16_t* qb = qk + (qkrow0 + qB + w * 16 + m16) * 4096;
#pragma unroll
    for (int kk = 0; kk < 4; ++kk) {
      const int col = (kk >> 1) * 1024 + h * 64 + (kk & 1) * 32 + quad * 8;
      qfA[kk] = *(const short8*)(qa + col);
      qfB[kk] = *(const short8*)(qb + col);
    }
  }
  f32x4 oA[9], oB[9];
#pragma unroll
  for (int j = 0; j < 9; ++j) { oA[j] = (f32x4){0.f,0.f,0.f,0.f}; oB[j] = (f32x4){0.f,0.f,0.f,0.f}; }

  const int qrowA = qA + w * 16 + quad * 4;
  const int qrowB = qB + w * 16 + quad * 4;

  // staging geometry
  const int kl4 = lane >> 4, kl15 = lane & 15;   // K tile: 4 rows/instr (256 B rows)
  const int vl3 = lane >> 3;                     // V tile: 8 rows/instr (128 B rows)
  const int vg7 = ((lane & 7) ^ vl3) * 8;

  for (int t = 0; t < nT; ++t) {
    const int k0 = t * 64;
    __syncthreads();
    // stage K: 64 rows x 128 elem (Kr|Ki of head h); row&7 = (i*4 + lane>>4)&7
#pragma unroll
    for (int i = 0; i < 4; ++i) {
      const int row = w * 16 + i * 4 + kl4;
      const int g = kl15 ^ (row & 7);            // low-3 XOR; bit3 of kl15 preserved
      const int col = 2048 + (g >> 3) * 1024 + h * 64 + (g & 7) * 8;
      gload_lds16(qk + (qkrow0 + k0 + row) * 4096 + col,
                  sK + (size_t)(w * 16 + i * 4) * 128 + lane * 8);
    }
    // stage V^T: 128 d-rows x 64 k; row&7 = lane>>3
#pragma unroll
    for (int i = 0; i < 4; ++i) {
      const int row = w * 32 + i * 8 + vl3;
      gload_lds16(vt + ((size_t)bh * 128 + row) * 2048 + k0 + vg7,
                  sV + (size_t)(w * 32 + i * 8) * 64 + lane * 8);
    }
    __syncthreads();

    const bool aAct = (t <= x);
    const bool dgA = (t == x), dgB = (t == nT - 1);

    // ---- S = Qs·K^T; joint over both subtiles per K-frag read
    f32x4 sAv[4], sBv[4];
    if (aAct) {
#pragma unroll
      for (int jt = 0; jt < 4; ++jt) {
        f32x4 a1 = (f32x4){0.f,0.f,0.f,0.f}, a2 = (f32x4){0.f,0.f,0.f,0.f};
#pragma unroll
        for (int kk = 0; kk < 4; ++kk) {
          short8 kf = *(const short8*)(sK + (jt * 16 + m16) * 128 +
                                       ((kk * 4 + quad) ^ swz7) * 8);
          a1 = __builtin_amdgcn_mfma_f32_16x16x32_bf16(qfA[kk], kf, a1, 0, 0, 0);
          a2 = __builtin_amdgcn_mfma_f32_16x16x32_bf16(qfB[kk], kf, a2, 0, 0, 0);
        }
        sAv[jt] = a1; sBv[jt] = a2;
      }
    } else {
#pragma unroll
      for (int jt = 0; jt < 4; ++jt) {
        f32x4 a2 = (f32x4){0.f,0.f,0.f,0.f};
#pragma unroll
        for (int kk = 0; kk < 4; ++kk) {
          short8 kf = *(const short8*)(sK + (jt * 16 + m16) * 128 +
                                       ((kk * 4 + quad) ^ swz7) * 8);
          a2 = __builtin_amdgcn_mfma_f32_16x16x32_bf16(qfB[kk], kf, a2, 0, 0, 0);
        }
        sBv[jt] = a2;
      }
    }

    // ---- fixed-max softmax: P = exp(S), C-layout -> A-layout via per-wave sP
    if (aAct) {
      bf16_t* pw = sP[w][0];
#pragma unroll
      for (int jt = 0; jt < 4; ++jt)
#pragma unroll
        for (int r = 0; r < 4; ++r) {
          float s = sAv[jt][r];
          if (dgA && (k0 + jt * 16 + m16 > qrowA + r)) s = -1e30f;
          pw[(quad * 4 + r) * 72 + jt * 16 + m16] = __float2bfloat16(__expf(s));
        }
    }
    {
      bf16_t* pw = sP[w][1];
#pragma unroll
      for (int jt = 0; jt < 4; ++jt)
#pragma unroll
        for (int r = 0; r < 4; ++r) {
          float s = sBv[jt][r];
          if (dgB && (k0 + jt * 16 + m16 > qrowB + r)) s = -1e30f;
          pw[(quad * 4 + r) * 72 + jt * 16 + m16] = __float2bfloat16(__expf(s));
        }
    }
    asm volatile("s_waitcnt lgkmcnt(0)" ::: "memory");  // own-wave P write->read

    // ---- O += P·V (j=8 = ones-row -> row sums l); joint per V-frag read
    if (aAct) {
#pragma unroll
      for (int kc = 0; kc < 2; ++kc) {
        short8 pA = *(const short8*)(sP[w][0] + m16 * 72 + kc * 32 + quad * 8);
        short8 pB = *(const short8*)(sP[w][1] + m16 * 72 + kc * 32 + quad * 8);
#pragma unroll
        for (int j = 0; j < 9; ++j) {
          short8 vf = *(const short8*)(sV + (j * 16 + m16) * 64 +
                                       ((kc * 4 + quad) ^ swz7) * 8);
          oA[j] = __builtin_amdgcn_mfma_f32_16x16x32_bf16(pA, vf, oA[j], 0, 0, 0);
          oB[j] = __builtin_amdgcn_mfma_f32_16x16x32_bf16(pB, vf, oB[j], 0, 0, 0);
        }
      }
    } else {
#pragma unroll
      for (int kc = 0; kc < 2; ++kc) {
        short8 pB = *(const short8*)(sP[w][1] + m16 * 72 + kc * 32 + quad * 8);
#pragma unroll
        for (int j = 0; j < 9; ++j) {
          short8 vf = *(const short8*)(sV + (j * 16 + m16) * 64 +
                                       ((kc * 4 + quad) ^ swz7) * 8);
          oB[j] = __builtin_amdgcn_mfma_f32_16x16x32_bf16(pB, vf, oB[j], 0, 0, 0);
        }
      }
    }
  }

  // ---- epilogue: l broadcast from lane (quad*16), normalize, write [B,L,2048]=[out_r|out_i]
#pragma unroll
  for (int part = 0; part < 2; ++part) {
    f32x4* o = part ? oB : oA;
    const int qrow = part ? qrowB : qrowA;
    float inv[4];
#pragma unroll
    for (int r = 0; r < 4; ++r)
      inv[r] = 1.f / __shfl(o[8][r], lane & 48);
#pragma unroll
    for (int j = 0; j < 8; ++j) {
      const int d = j * 16 + m16;
      const int col = (d < 64) ? (h * 64 + d) : (1024 + h * 64 + (d - 64));
#pragma unroll
      for (int r = 0; r < 4; ++r)
        acat[((size_t)b * 2048 + qrow + r) * 2048 + col] = __float2bfloat16(o[j][r] * inv[r]);
    }
  }
}

// ---------------------------------------------------------------- launch
extern "C" void kernel_launch(void* const* d_in, const int* in_sizes, int n_in,
                              void* d_out, int out_size, void* d_ws, size_t ws_size,
                              hipStream_t stream) {
  const float* xr  = (const float*)d_in[0];
  const float* xi  = (const float*)d_in[1];
  const float* wqr = (const float*)d_in[2];
  const float* wqi = (const float*)d_in[3];
  const float* wkr = (const float*)d_in[4];
  const float* wki = (const float*)d_in[5];
  const float* wvr = (const float*)d_in[6];
  const float* wvi = (const float*)d_in[7];
  const float* wor = (const float*)d_in[8];
  const float* woi = (const float*)d_in[9];
  const float* bor = (const float*)d_in[10];
  const float* boi = (const float*)d_in[11];
  float* out = (float*)d_out;

  char* ws = (char*)d_ws;
  bf16_t* Xcat = (bf16_t*)(ws);                   // 4096x2048   16 MB
  bf16_t* Wqkv = (bf16_t*)(ws + 16777216ull);     // 6144x2048   24 MB
  bf16_t* QKb  = (bf16_t*)(ws + 41943040ull);     // 4096x4096   32 MB
  bf16_t* Vt   = (bf16_t*)(ws + 75497472ull);     // 4096x2048   16 MB (V transposed)
  bf16_t* Acat = (bf16_t*)(ws + 92274688ull);     // 4096x2048   16 MB
  bf16_t* Wo   = (bf16_t*)(ws + 109051904ull);    // 2048x2048    8 MB

  pack_x_k<<<2048, 256, 0, stream>>>(xr, xi, Xcat);
  pack_wqkv_k<<<2048, 256, 0, stream>>>(wqr, wqi, wkr, wki, wvr, wvi, Wqkv);
  pack_wo_k<<<1024, 256, 0, stream>>>(wor, woi, Wo);
  gemm_qkv_k<<<dim3(32, 48), 320, 0, stream>>>(Xcat, Wqkv, QKb, Vt);
  attn_k<<<dim3(16, 32), 256, 0, stream>>>(QKb, Vt, Acat);
  gemm_out_k<<<dim3(32, 16), 320, 0, stream>>>(Acat, Wo, bor, boi, out);
}